// Round 7
// baseline (3026.829 us; speedup 1.0000x reference)
//
#include <hip/hip_runtime.h>

typedef unsigned short u16;
typedef __bf16 bf16x8 __attribute__((ext_vector_type(8)));
typedef float f32x4 __attribute__((ext_vector_type(4)));
typedef unsigned short u16x4 __attribute__((ext_vector_type(4)));

__device__ __forceinline__ u16 f2bf(float f) {
  union { float f; unsigned int u; } v; v.f = f;
  return (u16)((v.u + 0x7FFFu + ((v.u >> 16) & 1u)) >> 16);
}

__device__ __forceinline__ void gload16(const void* g, void* l) {
  __builtin_amdgcn_global_load_lds(
      (const __attribute__((address_space(1))) unsigned int*)g,
      (__attribute__((address_space(3))) unsigned int*)l, 16, 0, 0);
}

// ---------------------------------------------------------------------------
// Weight prep
// ---------------------------------------------------------------------------
__global__ void transpose_cast_kernel(const float* __restrict__ W, u16* __restrict__ WT,
                                      int R, int C) {
  __shared__ float tile[32][33];
  const int tx = threadIdx.x, ty = threadIdx.y;
  const size_t zoff = (size_t)blockIdx.z * R * C;
  const int c0 = blockIdx.x * 32, r0 = blockIdx.y * 32;
#pragma unroll
  for (int k = 0; k < 32; k += 8)
    tile[ty + k][tx] = W[zoff + (size_t)(r0 + ty + k) * C + (c0 + tx)];
  __syncthreads();
#pragma unroll
  for (int k = 0; k < 32; k += 8)
    WT[zoff + (size_t)(c0 + ty + k) * R + (r0 + tx)] = f2bf(tile[tx][ty + k]);
}

// lm_head (50257 x 1024 f32) -> bf16 padded to 50432 rows (pad rows zero)
__global__ void lm_cast_kernel(const float* __restrict__ lm, u16* __restrict__ out) {
  const int row = blockIdx.x;
  const int t = threadIdx.x;
  u16x4 o = {0, 0, 0, 0};
  if (row < 50257) {
    float4 v = *(const float4*)(lm + (size_t)row * 1024 + t * 4);
    o.x = f2bf(v.x); o.y = f2bf(v.y); o.z = f2bf(v.z); o.w = f2bf(v.w);
  }
  *(u16x4*)(out + (size_t)row * 1024 + t * 4) = o;
}

__global__ void embed_kernel(const int* __restrict__ ids, const float* __restrict__ embed,
                             float* __restrict__ x) {
  const int row = blockIdx.x;
  const int id = ids[row];
  const int t = threadIdx.x;
  *(float4*)(x + (size_t)row * 1024 + t * 4) =
      *(const float4*)(embed + (size_t)id * 1024 + t * 4);
}

// ---------------------------------------------------------------------------
// RMSNorm: f32 in -> bf16 out (D = 1024, one block per row)
// ---------------------------------------------------------------------------
__global__ void rmsnorm_kernel(const float* __restrict__ x, const float* __restrict__ w,
                               u16* __restrict__ out) {
  const int row = blockIdx.x, tid = threadIdx.x;
  const float* xr = x + (size_t)row * 1024;
  float4 v = *(const float4*)(xr + tid * 4);
  float ss = v.x * v.x + v.y * v.y + v.z * v.z + v.w * v.w;
#pragma unroll
  for (int off = 32; off; off >>= 1) ss += __shfl_xor(ss, off);
  __shared__ float red[4];
  if ((tid & 63) == 0) red[tid >> 6] = ss;
  __syncthreads();
  const float tot = red[0] + red[1] + red[2] + red[3];
  const float r = rsqrtf(tot * (1.0f / 1024.0f) + 1e-6f);
  float4 wv = *(const float4*)(w + tid * 4);
  u16x4 o;
  o.x = f2bf(v.x * r * wv.x); o.y = f2bf(v.y * r * wv.y);
  o.z = f2bf(v.z * r * wv.z); o.w = f2bf(v.w * r * wv.w);
  *(u16x4*)(out + (size_t)row * 1024 + tid * 4) = o;
}

// ---------------------------------------------------------------------------
// Sequential chaotic scan: single pre buffer, b_in folded.
// r-space recurrence (s = 1-2r): z = fma(-2A2, r, A2b + 2L*p); r = rcp(1+exp2(z))
// ---------------------------------------------------------------------------
__device__ __forceinline__ void sload(const float* __restrict__ p, int tb,
                                      float A2b, float (&buf)[8]) {
#pragma unroll
  for (int j = 0; j < 8; j++)
    buf[j] = fmaf(p[(size_t)(tb + j) * 1024], 2.8853900817779268f, A2b);
}

__device__ __forceinline__ void scomp(float (&buf)[8], float m2A2, float& r,
                                      u16* __restrict__ o, int tb) {
#pragma unroll
  for (int j = 0; j < 8; j++) {
    float z = fmaf(m2A2, r, buf[j]);
    float e = __builtin_amdgcn_exp2f(z);
    r = __builtin_amdgcn_rcpf(1.0f + e);
    o[(size_t)(tb + j) * 1024] = f2bf(fmaf(-2.0f, r, 1.0f));
  }
}

__global__ __launch_bounds__(256) void scan_kernel(const float* __restrict__ pre,
                                                   const float* __restrict__ a_diag,
                                                   const float* __restrict__ b_in,
                                                   u16* __restrict__ hs) {
  const int T = 2048;
  const int idx = blockIdx.x * 256 + threadIdx.x;  // 0..2047
  const int b = idx >> 10, d = idx & 1023;
  const float* p = pre + (size_t)b * T * 1024 + d;
  u16* o = hs + (size_t)b * T * 1024 + d;
  const float A2 = a_diag[d] * 2.8853900817779268f;
  const float A2b = fmaf(2.8853900817779268f, b_in[d], A2);
  const float m2A2 = -2.0f * A2;
  float r = 0.5f;
  float b0[8], b1[8], b2[8], b3[8];
  sload(p, 0, A2b, b0); sload(p, 8, A2b, b1);
  sload(p, 16, A2b, b2); sload(p, 24, A2b, b3);
  for (int t0 = 0; t0 < T; t0 += 32) {
    scomp(b0, m2A2, r, o, t0);
    if (t0 + 32 < T) sload(p, t0 + 32, A2b, b0);
    scomp(b1, m2A2, r, o, t0 + 8);
    if (t0 + 32 < T) sload(p, t0 + 40, A2b, b1);
    scomp(b2, m2A2, r, o, t0 + 16);
    if (t0 + 32 < T) sload(p, t0 + 48, A2b, b2);
    scomp(b3, m2A2, r, o, t0 + 24);
    if (t0 + 32 < T) sload(p, t0 + 56, A2b, b3);
  }
}

// ---------------------------------------------------------------------------
// gemmL: layer GEMM, NT bf16. C(M x N) = A(M x K) @ B(N x K)^T.
// 64x128 tile, BK=64, 4 waves (each 64 rows x 32 cols), counted-vmcnt(6)
// 2-phase dbuf. No split-K (kills f32 partial traffic); residual/bias/silu
// fused in epilogue. Grid (N/128, M/64) = 512+ blocks = 2+/CU (48KB LDS).
// bid%8 XCD round-robin -> one B col-panel (256KB) resident per XCD L2.
// LDS swizzle: row=128B=8 slots, slot ^= row&7 (both-sides, rule #21).
// EPI: 0 Cf=v; 1 Cf+=v; 2 Cb=silu(v+bias); 3 Cf+=v+bias
// ---------------------------------------------------------------------------
template <int EPI>
__global__ __launch_bounds__(256) void gemmL(
    const u16* __restrict__ A, int lda, const u16* __restrict__ Bw, int ldb,
    const float* __restrict__ bias, float* Cf, u16* __restrict__ Cb,
    int ldc, int K) {
  __shared__ char lds[49152];  // 2 x [A 8K | B 16K]
  const int tid = threadIdx.x;
  const int lane = tid & 63;
  const int wc = tid >> 6;  // wave -> col quarter
  const int tm = blockIdx.y * 64, tn = blockIdx.x * 128;
  const int lr = lane & 15;
  const int sb0 = ((lane >> 4) ^ (lane & 7)) << 4;

  const int srow = tid >> 3;  // 0..31
  const int sxs = ((tid & 7) ^ (srow & 7)) << 4;
  const char* pA = (const char*)A + (size_t)(tm + srow) * lda * 2 + sxs;
  const char* pB = (const char*)Bw + (size_t)(tn + srow) * ldb * 2 + sxs;
  const size_t a32 = (size_t)lda * 64;  // +32 rows (bytes)
  const size_t b32 = (size_t)ldb * 64;

#define STGL(kt, bufo)                                \
  {                                                   \
    char* d = lds + (bufo) + tid * 16;                \
    const size_t kb = (size_t)(kt) << 7;              \
    gload16(pA + kb, d);                              \
    gload16(pA + a32 + kb, d + 4096);                 \
    gload16(pB + kb, d + 8192);                       \
    gload16(pB + b32 + kb, d + 12288);                \
    gload16(pB + 2 * b32 + kb, d + 16384);            \
    gload16(pB + 3 * b32 + kb, d + 20480);            \
  }

  f32x4 acc[4][2] = {};
  const int nkt = K >> 6;

  STGL(0, 0);
  int cur = 0;
  for (int kt = 0; kt < nkt; ++kt) {
    if (kt + 1 < nkt) {
      STGL(kt + 1, (cur ^ 1) * 24576);
      asm volatile("s_waitcnt vmcnt(6)" ::: "memory");
    } else {
      asm volatile("s_waitcnt vmcnt(0)" ::: "memory");
    }
    __builtin_amdgcn_s_barrier();
    const char* base = lds + cur * 24576;
    bf16x8 aF[4][2], bF[2][2];
#pragma unroll
    for (int m = 0; m < 4; m++)
#pragma unroll
      for (int ks = 0; ks < 2; ks++)
        aF[m][ks] =
            *(const bf16x8*)(base + (m * 16 + lr) * 128 + (sb0 ^ (ks << 6)));
#pragma unroll
    for (int n = 0; n < 2; n++)
#pragma unroll
      for (int ks = 0; ks < 2; ks++)
        bF[n][ks] = *(const bf16x8*)(base + 8192 +
                                     (wc * 32 + n * 16 + lr) * 128 +
                                     (sb0 ^ (ks << 6)));
#pragma unroll
    for (int ks = 0; ks < 2; ks++)
#pragma unroll
      for (int m = 0; m < 4; m++)
#pragma unroll
        for (int n = 0; n < 2; n++)
          acc[m][n] = __builtin_amdgcn_mfma_f32_16x16x32_bf16(
              aF[m][ks], bF[n][ks], acc[m][n], 0, 0, 0);
    __builtin_amdgcn_s_barrier();
    cur ^= 1;
  }
#undef STGL

  // C/D layout: col = lane&15, row = (lane>>4)*4 + j
  const int crow = tm + ((lane >> 4) << 2);
  const int ccol = tn + wc * 32 + lr;
#pragma unroll
  for (int m = 0; m < 4; m++) {
#pragma unroll
    for (int n = 0; n < 2; n++) {
      const int cg = ccol + n * 16;
      float bb = 0.0f;
      if (EPI == 2 || EPI == 3) bb = bias[cg];
#pragma unroll
      for (int j = 0; j < 4; j++) {
        const size_t off = (size_t)(crow + m * 16 + j) * ldc + cg;
        const float v = acc[m][n][j] + bb;
        if (EPI == 0) {
          Cf[off] = v;
        } else if (EPI == 1) {
          Cf[off] += v;
        } else if (EPI == 2) {
          const float sg = __builtin_amdgcn_rcpf(
              1.0f + __builtin_amdgcn_exp2f(-1.4426950408889634f * v));
          Cb[off] = f2bf(v * sg);
        } else {
          Cf[off] += v;
        }
      }
    }
  }
}

// ---------------------------------------------------------------------------
// gemm_lm8: 256x256 / BK=64 / 8 waves / 8-phase counted-vmcnt (round-5
// validated, 527us) + NONTEMPORAL C stores (C is final output, never read;
// bypassing L2/L3 keeps the B panel resident -> less B re-fetch).
// ---------------------------------------------------------------------------
__global__ __launch_bounds__(512, 2) void gemm_lm8(
    const u16* __restrict__ A, const u16* __restrict__ Bw,
    float* __restrict__ C, int Nreal) {
  __shared__ char lds[131072];
  const int tid = threadIdx.x;
  const int lane = tid & 63;
  const int wid = tid >> 6;
  const int wr = wid >> 2;
  const int wc = wid & 3;
  const int bid = blockIdx.x;
  const int tm = (((bid & 7) << 1) + ((bid >> 3) & 1)) << 8;
  const int tn = (bid >> 4) << 8;

  const int srow = tid >> 3;
  const int sxor = ((tid & 7) ^ (srow & 7)) << 4;
  const char* pAs = (const char*)A + ((size_t)(tm + srow) << 11) + sxor;
  const char* pBs = (const char*)Bw + ((size_t)(tn + srow) << 11) + sxor;

#define STG(p, h, kt, ro)                                      \
  {                                                            \
    char* d = lds + (ro) + tid * 16;                           \
    const char* s = (p) + ((size_t)(h) << 18) + ((kt) << 7);   \
    gload16(s, d);                                             \
    gload16(s + (64ull << 11), d + 8192);                      \
  }

  const int lr = lane & 15;
  const int sb0 = (((lane >> 4) ^ (lane & 7)) << 4);
  const int sb[2] = {sb0, sb0 ^ 64};
  const int aB = wr * 16384 + lr * 128;
  const int bB = 32768 + (wc >> 1) * 16384 + ((wc & 1) * 64 + lr) * 128;

  bf16x8 aR[4][2], bR[2][2][2];
  f32x4 acc[8][4] = {};

#define LDA_Q(bufo, mq)                                                         \
  _Pragma("unroll") for (int m_ = 0; m_ < 4; m_++)                              \
  _Pragma("unroll") for (int k_ = 0; k_ < 2; k_++)                              \
      aR[m_][k_] = *(const bf16x8*)(lds + (bufo) + aB + (mq)*8192 + m_*2048 + sb[k_]);

#define LDB_Q(bufo, nq)                                                         \
  _Pragma("unroll") for (int n_ = 0; n_ < 2; n_++)                              \
  _Pragma("unroll") for (int k_ = 0; k_ < 2; k_++)                              \
      bR[nq][n_][k_] = *(const bf16x8*)(lds + (bufo) + bB + (nq)*4096 + n_*2048 + sb[k_]);

#define MFMA_Q(mq, nq)                                                          \
  __builtin_amdgcn_s_setprio(1);                                                \
  _Pragma("unroll") for (int m_ = 0; m_ < 4; m_++)                              \
  _Pragma("unroll") for (int n_ = 0; n_ < 2; n_++)                              \
  _Pragma("unroll") for (int k_ = 0; k_ < 2; k_++)                              \
      acc[(mq)*4 + m_][(nq)*2 + n_] = __builtin_amdgcn_mfma_f32_16x16x32_bf16(  \
          aR[m_][k_], bR[nq][n_][k_], acc[(mq)*4 + m_][(nq)*2 + n_], 0, 0, 0);  \
  __builtin_amdgcn_s_setprio(0);

#define BAR() __builtin_amdgcn_s_barrier()
#define LGKM0() asm volatile("s_waitcnt lgkmcnt(0)" ::: "memory")

  STG(pAs, 0, 0, 0);
  STG(pAs, 1, 0, 16384);
  STG(pBs, 0, 0, 32768);
  STG(pBs, 1, 0, 49152);
  STG(pBs, 0, 1, 65536 + 32768);
  STG(pBs, 1, 1, 65536 + 49152);
  asm volatile("s_waitcnt vmcnt(4)" ::: "memory");
  BAR();

  for (int it = 0; it < 8; ++it) {
    const int t1 = 2 * it + 1, t2 = 2 * it + 2, t3 = 2 * it + 3;
    const bool st = (it < 7);
    LDA_Q(0, 0); LDB_Q(0, 0);
    STG(pAs, 0, t1, 65536);
    BAR(); LGKM0(); MFMA_Q(0, 0); BAR();
    LDB_Q(0, 1);
    STG(pAs, 1, t1, 65536 + 16384);
    BAR(); LGKM0(); MFMA_Q(0, 1); BAR();
    LDA_Q(0, 1);
    if (st) STG(pBs, 0, t2, 32768);
    BAR(); LGKM0(); MFMA_Q(1, 0); BAR();
    if (st) STG(pBs, 1, t2, 49152);
    BAR(); LGKM0(); MFMA_Q(1, 1);
    if (st) { asm volatile("s_waitcnt vmcnt(4)" ::: "memory"); }
    else    { asm volatile("s_waitcnt vmcnt(0)" ::: "memory"); }
    BAR();
    LDA_Q(65536, 0); LDB_Q(65536, 0);
    if (st) STG(pAs, 0, t2, 0);
    BAR(); LGKM0(); MFMA_Q(0, 0); BAR();
    LDB_Q(65536, 1);
    if (st) STG(pAs, 1, t2, 16384);
    BAR(); LGKM0(); MFMA_Q(0, 1); BAR();
    LDA_Q(65536, 1);
    if (st) STG(pBs, 0, t3, 65536 + 32768);
    BAR(); LGKM0(); MFMA_Q(1, 0); BAR();
    if (st) STG(pBs, 1, t3, 65536 + 49152);
    BAR(); LGKM0(); MFMA_Q(1, 1);
    if (st) { asm volatile("s_waitcnt vmcnt(4)" ::: "memory"); }
    else    { asm volatile("s_waitcnt vmcnt(0)" ::: "memory"); }
    BAR();
  }
#undef STG
#undef LDA_Q
#undef LDB_Q
#undef MFMA_Q
#undef BAR
#undef LGKM0

  const int crow = tm + wr * 128 + ((lane >> 4) << 2);
  const int ccol = tn + wc * 64 + lr;
#pragma unroll
  for (int M_ = 0; M_ < 8; M_++) {
    const int r = crow + (M_ >> 2) * 64 + (M_ & 3) * 16;
#pragma unroll
    for (int N_ = 0; N_ < 4; N_++) {
      const int cg = ccol + (N_ >> 1) * 32 + (N_ & 1) * 16;
      if (cg < Nreal) {
#pragma unroll
        for (int j = 0; j < 4; j++)
          __builtin_nontemporal_store(acc[M_][N_][j],
                                      &C[(size_t)(r + j) * Nreal + cg]);
      }
    }
  }
}

// ---------------------------------------------------------------------------
// Host
// ---------------------------------------------------------------------------
extern "C" void kernel_launch(void* const* d_in, const int* in_sizes, int n_in,
                              void* d_out, int out_size, void* d_ws, size_t ws_size,
                              hipStream_t stream) {
  const int D = 1024, V = 50257, L = 8;
  const int M = 4096;
  const int Vpad = 50432;  // 197 * 256
  const size_t MD = (size_t)M * D;

  const int* ids = (const int*)d_in[0];
  const float* embedw = (const float*)d_in[1];
  const float* norm1_w = (const float*)d_in[2];
  const float* norm2_w = (const float*)d_in[3];
  const float* a_diag = (const float*)d_in[4];
  const float* W_in = (const float*)d_in[5];
  const float* b_in = (const float*)d_in[6];
  const float* W_out = (const float*)d_in[7];
  const float* ff_w1 = (const float*)d_in[8];
  const float* ff_b1 = (const float*)d_in[9];
  const float* ff_w2 = (const float*)d_in[10];
  const float* ff_b2 = (const float*)d_in[11];
  const float* final_norm_w = (const float*)d_in[12];
  const float* lm_head_w = (const float*)d_in[13];

  char* w = (char*)d_ws;
  float* x = (float*)w;   w += MD * 4;
  u16* h = (u16*)w;       w += MD * 2;
  float* pre = (float*)w; w += MD * 4;
  u16* hs = (u16*)w;      w += MD * 2;
  u16* hff = (u16*)w;     w += MD * 2 * 2;
  u16* WinT = (u16*)w;    w += (size_t)L * D * D * 2;
  u16* WoutT = (u16*)w;   w += (size_t)L * D * D * 2;
  u16* ffw1T = (u16*)w;   w += (size_t)L * 2 * D * D * 2;
  u16* ffw2T = (u16*)w;   w += (size_t)L * 2 * D * D * 2;
  u16* lmpad = (u16*)w;   w += (size_t)Vpad * D * 2;

  // weight prep
  lm_cast_kernel<<<Vpad, 256, 0, stream>>>(lm_head_w, lmpad);
  transpose_cast_kernel<<<dim3(32, 32, L), dim3(32, 8), 0, stream>>>(W_in, WinT, D, D);
  transpose_cast_kernel<<<dim3(64, 32, L), dim3(32, 8), 0, stream>>>(ff_w1, ffw1T, D, 2 * D);
  transpose_cast_kernel<<<dim3(32, 32, L), dim3(32, 8), 0, stream>>>(W_out, WoutT, D, D);
  transpose_cast_kernel<<<dim3(32, 64, L), dim3(32, 8), 0, stream>>>(ff_w2, ffw2T, 2 * D, D);

  embed_kernel<<<M, 256, 0, stream>>>(ids, embedw, x);

  for (int l = 0; l < L; l++) {
    rmsnorm_kernel<<<M, 256, 0, stream>>>(x, norm1_w + (size_t)l * D, h);
    // GEMM1: pre = h @ WinT  (b_in folded into scan)
    gemmL<0><<<dim3(8, 64), 256, 0, stream>>>(
        h, D, WinT + (size_t)l * D * D, D, nullptr, pre, nullptr, D, D);
    scan_kernel<<<8, 256, 0, stream>>>(pre, a_diag + (size_t)l * D,
                                       b_in + (size_t)l * D, hs);
    // GEMM2: x += hs @ WoutT
    gemmL<1><<<dim3(8, 64), 256, 0, stream>>>(
        hs, D, WoutT + (size_t)l * D * D, D, nullptr, x, nullptr, D, D);
    rmsnorm_kernel<<<M, 256, 0, stream>>>(x, norm2_w + (size_t)l * D, h);
    // FF1: hff = silu(h @ ffw1T + b1)
    gemmL<2><<<dim3(16, 64), 256, 0, stream>>>(
        h, D, ffw1T + (size_t)l * 2 * D * D, D, ff_b1 + (size_t)l * 2 * D,
        nullptr, hff, 2 * D, D);
    // FF2: x += hff @ ffw2T + b2
    gemmL<3><<<dim3(8, 64), 256, 0, stream>>>(
        hff, 2 * D, ffw2T + (size_t)l * 2 * D * D, 2 * D,
        ff_b2 + (size_t)l * D, x, nullptr, D, 2 * D);
  }

  rmsnorm_kernel<<<M, 256, 0, stream>>>(x, final_norm_w, h);
  gemm_lm8<<<dim3(8 * 394), 512, 0, stream>>>(h, lmpad, (float*)d_out, V);
}

// Round 8
// 2638.573 us; speedup vs baseline: 1.1471x; 1.1471x over previous
//
#include <hip/hip_runtime.h>

typedef unsigned short u16;
typedef __bf16 bf16x8 __attribute__((ext_vector_type(8)));
typedef float f32x4 __attribute__((ext_vector_type(4)));
typedef unsigned short u16x4 __attribute__((ext_vector_type(4)));

__device__ __forceinline__ u16 f2bf(float f) {
  union { float f; unsigned int u; } v; v.f = f;
  return (u16)((v.u + 0x7FFFu + ((v.u >> 16) & 1u)) >> 16);
}

__device__ __forceinline__ void gload16(const void* g, void* l) {
  __builtin_amdgcn_global_load_lds(
      (const __attribute__((address_space(1))) unsigned int*)g,
      (__attribute__((address_space(3))) unsigned int*)l, 16, 0, 0);
}

// ---------------------------------------------------------------------------
// Weight prep
// ---------------------------------------------------------------------------
__global__ void transpose_cast_kernel(const float* __restrict__ W, u16* __restrict__ WT,
                                      int R, int C) {
  __shared__ float tile[32][33];
  const int tx = threadIdx.x, ty = threadIdx.y;
  const size_t zoff = (size_t)blockIdx.z * R * C;
  const int c0 = blockIdx.x * 32, r0 = blockIdx.y * 32;
#pragma unroll
  for (int k = 0; k < 32; k += 8)
    tile[ty + k][tx] = W[zoff + (size_t)(r0 + ty + k) * C + (c0 + tx)];
  __syncthreads();
#pragma unroll
  for (int k = 0; k < 32; k += 8)
    WT[zoff + (size_t)(c0 + ty + k) * R + (r0 + tx)] = f2bf(tile[tx][ty + k]);
}

// lm_head (50257 x 1024 f32) -> bf16 padded to 50432 rows (pad rows zero)
__global__ void lm_cast_kernel(const float* __restrict__ lm, u16* __restrict__ out) {
  const int row = blockIdx.x;
  const int t = threadIdx.x;
  u16x4 o = {0, 0, 0, 0};
  if (row < 50257) {
    float4 v = *(const float4*)(lm + (size_t)row * 1024 + t * 4);
    o.x = f2bf(v.x); o.y = f2bf(v.y); o.z = f2bf(v.z); o.w = f2bf(v.w);
  }
  *(u16x4*)(out + (size_t)row * 1024 + t * 4) = o;
}

__global__ void embed_kernel(const int* __restrict__ ids, const float* __restrict__ embed,
                             float* __restrict__ x) {
  const int row = blockIdx.x;
  const int id = ids[row];
  const int t = threadIdx.x;
  *(float4*)(x + (size_t)row * 1024 + t * 4) =
      *(const float4*)(embed + (size_t)id * 1024 + t * 4);
}

// ---------------------------------------------------------------------------
// RMSNorm: f32 in -> bf16 out (D = 1024, one block per row)
// ---------------------------------------------------------------------------
__global__ void rmsnorm_kernel(const float* __restrict__ x, const float* __restrict__ w,
                               u16* __restrict__ out) {
  const int row = blockIdx.x, tid = threadIdx.x;
  const float* xr = x + (size_t)row * 1024;
  float4 v = *(const float4*)(xr + tid * 4);
  float ss = v.x * v.x + v.y * v.y + v.z * v.z + v.w * v.w;
#pragma unroll
  for (int off = 32; off; off >>= 1) ss += __shfl_xor(ss, off);
  __shared__ float red[4];
  if ((tid & 63) == 0) red[tid >> 6] = ss;
  __syncthreads();
  const float tot = red[0] + red[1] + red[2] + red[3];
  const float r = rsqrtf(tot * (1.0f / 1024.0f) + 1e-6f);
  float4 wv = *(const float4*)(w + tid * 4);
  u16x4 o;
  o.x = f2bf(v.x * r * wv.x); o.y = f2bf(v.y * r * wv.y);
  o.z = f2bf(v.z * r * wv.z); o.w = f2bf(v.w * r * wv.w);
  *(u16x4*)(out + (size_t)row * 1024 + tid * 4) = o;
}

// ---------------------------------------------------------------------------
// Sequential chaotic scan: single pre buffer, b_in folded.
// ---------------------------------------------------------------------------
__device__ __forceinline__ void sload(const float* __restrict__ p, int tb,
                                      float A2b, float (&buf)[8]) {
#pragma unroll
  for (int j = 0; j < 8; j++)
    buf[j] = fmaf(p[(size_t)(tb + j) * 1024], 2.8853900817779268f, A2b);
}

__device__ __forceinline__ void scomp(float (&buf)[8], float m2A2, float& r,
                                      u16* __restrict__ o, int tb) {
#pragma unroll
  for (int j = 0; j < 8; j++) {
    float z = fmaf(m2A2, r, buf[j]);
    float e = __builtin_amdgcn_exp2f(z);
    r = __builtin_amdgcn_rcpf(1.0f + e);
    o[(size_t)(tb + j) * 1024] = f2bf(fmaf(-2.0f, r, 1.0f));
  }
}

__global__ __launch_bounds__(256) void scan_kernel(const float* __restrict__ pre,
                                                   const float* __restrict__ a_diag,
                                                   const float* __restrict__ b_in,
                                                   u16* __restrict__ hs) {
  const int T = 2048;
  const int idx = blockIdx.x * 256 + threadIdx.x;  // 0..2047
  const int b = idx >> 10, d = idx & 1023;
  const float* p = pre + (size_t)b * T * 1024 + d;
  u16* o = hs + (size_t)b * T * 1024 + d;
  const float A2 = a_diag[d] * 2.8853900817779268f;
  const float A2b = fmaf(2.8853900817779268f, b_in[d], A2);
  const float m2A2 = -2.0f * A2;
  float r = 0.5f;
  float b0[8], b1[8], b2[8], b3[8];
  sload(p, 0, A2b, b0); sload(p, 8, A2b, b1);
  sload(p, 16, A2b, b2); sload(p, 24, A2b, b3);
  for (int t0 = 0; t0 < T; t0 += 32) {
    scomp(b0, m2A2, r, o, t0);
    if (t0 + 32 < T) sload(p, t0 + 32, A2b, b0);
    scomp(b1, m2A2, r, o, t0 + 8);
    if (t0 + 32 < T) sload(p, t0 + 40, A2b, b1);
    scomp(b2, m2A2, r, o, t0 + 16);
    if (t0 + 32 < T) sload(p, t0 + 48, A2b, b2);
    scomp(b3, m2A2, r, o, t0 + 24);
    if (t0 + 32 < T) sload(p, t0 + 56, A2b, b3);
  }
}

// ---------------------------------------------------------------------------
// gemmL: layer GEMM, NT bf16. 64x128 tile, BK=64, 4 waves, counted-vmcnt(6)
// 2-phase dbuf; residual/bias/silu fused in epilogue (round-7 validated).
// EPI: 0 Cf=v; 1 Cf+=v; 2 Cb=silu(v+bias); 3 Cf+=v+bias
// ---------------------------------------------------------------------------
template <int EPI>
__global__ __launch_bounds__(256) void gemmL(
    const u16* __restrict__ A, int lda, const u16* __restrict__ Bw, int ldb,
    const float* __restrict__ bias, float* Cf, u16* __restrict__ Cb,
    int ldc, int K) {
  __shared__ char lds[49152];  // 2 x [A 8K | B 16K]
  const int tid = threadIdx.x;
  const int lane = tid & 63;
  const int wc = tid >> 6;
  const int tm = blockIdx.y * 64, tn = blockIdx.x * 128;
  const int lr = lane & 15;
  const int sb0 = ((lane >> 4) ^ (lane & 7)) << 4;

  const int srow = tid >> 3;  // 0..31
  const int sxs = ((tid & 7) ^ (srow & 7)) << 4;
  const char* pA = (const char*)A + (size_t)(tm + srow) * lda * 2 + sxs;
  const char* pB = (const char*)Bw + (size_t)(tn + srow) * ldb * 2 + sxs;
  const size_t a32 = (size_t)lda * 64;
  const size_t b32 = (size_t)ldb * 64;

#define STGL(kt, bufo)                                \
  {                                                   \
    char* d = lds + (bufo) + tid * 16;                \
    const size_t kb = (size_t)(kt) << 7;              \
    gload16(pA + kb, d);                              \
    gload16(pA + a32 + kb, d + 4096);                 \
    gload16(pB + kb, d + 8192);                       \
    gload16(pB + b32 + kb, d + 12288);                \
    gload16(pB + 2 * b32 + kb, d + 16384);            \
    gload16(pB + 3 * b32 + kb, d + 20480);            \
  }

  f32x4 acc[4][2] = {};
  const int nkt = K >> 6;

  STGL(0, 0);
  int cur = 0;
  for (int kt = 0; kt < nkt; ++kt) {
    if (kt + 1 < nkt) {
      STGL(kt + 1, (cur ^ 1) * 24576);
      asm volatile("s_waitcnt vmcnt(6)" ::: "memory");
    } else {
      asm volatile("s_waitcnt vmcnt(0)" ::: "memory");
    }
    __builtin_amdgcn_s_barrier();
    const char* base = lds + cur * 24576;
    bf16x8 aF[4][2], bF[2][2];
#pragma unroll
    for (int m = 0; m < 4; m++)
#pragma unroll
      for (int ks = 0; ks < 2; ks++)
        aF[m][ks] =
            *(const bf16x8*)(base + (m * 16 + lr) * 128 + (sb0 ^ (ks << 6)));
#pragma unroll
    for (int n = 0; n < 2; n++)
#pragma unroll
      for (int ks = 0; ks < 2; ks++)
        bF[n][ks] = *(const bf16x8*)(base + 8192 +
                                     (wc * 32 + n * 16 + lr) * 128 +
                                     (sb0 ^ (ks << 6)));
#pragma unroll
    for (int ks = 0; ks < 2; ks++)
#pragma unroll
      for (int m = 0; m < 4; m++)
#pragma unroll
        for (int n = 0; n < 2; n++)
          acc[m][n] = __builtin_amdgcn_mfma_f32_16x16x32_bf16(
              aF[m][ks], bF[n][ks], acc[m][n], 0, 0, 0);
    __builtin_amdgcn_s_barrier();
    cur ^= 1;
  }
#undef STGL

  const int crow = tm + ((lane >> 4) << 2);
  const int ccol = tn + wc * 32 + lr;
#pragma unroll
  for (int m = 0; m < 4; m++) {
#pragma unroll
    for (int n = 0; n < 2; n++) {
      const int cg = ccol + n * 16;
      float bb = 0.0f;
      if (EPI == 2 || EPI == 3) bb = bias[cg];
#pragma unroll
      for (int j = 0; j < 4; j++) {
        const size_t off = (size_t)(crow + m * 16 + j) * ldc + cg;
        const float v = acc[m][n][j] + bb;
        if (EPI == 0) {
          Cf[off] = v;
        } else if (EPI == 1) {
          Cf[off] += v;
        } else if (EPI == 2) {
          const float sg = __builtin_amdgcn_rcpf(
              1.0f + __builtin_amdgcn_exp2f(-1.4426950408889634f * v));
          Cb[off] = f2bf(v * sg);
        } else {
          Cf[off] += v;
        }
      }
    }
  }
}

// ---------------------------------------------------------------------------
// gemm_lm8: 256x256 / BK=64 / 8 waves / 8-phase counted-vmcnt (round-5
// validated main loop) + NEW epilogue: stage each 128-row half of the C tile
// through LDS (XOR-swizzled, 2-way write conflict = free) and store each row
// as a contiguous 1KB wave-instruction, NONTEMPORAL. Full-line NT writes ->
// write-combining works (round-7's NT scatter doubled WRITE_SIZE) and C
// bypasses L2/L3 -> B col-tile window survives in L3 -> less B re-fetch.
// ---------------------------------------------------------------------------
__global__ __launch_bounds__(512, 2) void gemm_lm8(
    const u16* __restrict__ A, const u16* __restrict__ Bw,
    float* __restrict__ C, int Nreal) {
  __shared__ char lds[131072];
  const int tid = threadIdx.x;
  const int lane = tid & 63;
  const int wid = tid >> 6;
  const int wr = wid >> 2;
  const int wc = wid & 3;
  const int bid = blockIdx.x;
  const int tm = (((bid & 7) << 1) + ((bid >> 3) & 1)) << 8;
  const int tn = (bid >> 4) << 8;

  const int srow = tid >> 3;
  const int sxor = ((tid & 7) ^ (srow & 7)) << 4;
  const char* pAs = (const char*)A + ((size_t)(tm + srow) << 11) + sxor;
  const char* pBs = (const char*)Bw + ((size_t)(tn + srow) << 11) + sxor;

#define STG(p, h, kt, ro)                                      \
  {                                                            \
    char* d = lds + (ro) + tid * 16;                           \
    const char* s = (p) + ((size_t)(h) << 18) + ((kt) << 7);   \
    gload16(s, d);                                             \
    gload16(s + (64ull << 11), d + 8192);                      \
  }

  const int lr = lane & 15;
  const int sb0 = (((lane >> 4) ^ (lane & 7)) << 4);
  const int sb[2] = {sb0, sb0 ^ 64};
  const int aB = wr * 16384 + lr * 128;
  const int bB = 32768 + (wc >> 1) * 16384 + ((wc & 1) * 64 + lr) * 128;

  bf16x8 aR[4][2], bR[2][2][2];
  f32x4 acc[8][4] = {};

#define LDA_Q(bufo, mq)                                                         \
  _Pragma("unroll") for (int m_ = 0; m_ < 4; m_++)                              \
  _Pragma("unroll") for (int k_ = 0; k_ < 2; k_++)                              \
      aR[m_][k_] = *(const bf16x8*)(lds + (bufo) + aB + (mq)*8192 + m_*2048 + sb[k_]);

#define LDB_Q(bufo, nq)                                                         \
  _Pragma("unroll") for (int n_ = 0; n_ < 2; n_++)                              \
  _Pragma("unroll") for (int k_ = 0; k_ < 2; k_++)                              \
      bR[nq][n_][k_] = *(const bf16x8*)(lds + (bufo) + bB + (nq)*4096 + n_*2048 + sb[k_]);

#define MFMA_Q(mq, nq)                                                          \
  __builtin_amdgcn_s_setprio(1);                                                \
  _Pragma("unroll") for (int m_ = 0; m_ < 4; m_++)                              \
  _Pragma("unroll") for (int n_ = 0; n_ < 2; n_++)                              \
  _Pragma("unroll") for (int k_ = 0; k_ < 2; k_++)                              \
      acc[(mq)*4 + m_][(nq)*2 + n_] = __builtin_amdgcn_mfma_f32_16x16x32_bf16(  \
          aR[m_][k_], bR[nq][n_][k_], acc[(mq)*4 + m_][(nq)*2 + n_], 0, 0, 0);  \
  __builtin_amdgcn_s_setprio(0);

#define BAR() __builtin_amdgcn_s_barrier()
#define LGKM0() asm volatile("s_waitcnt lgkmcnt(0)" ::: "memory")

  STG(pAs, 0, 0, 0);
  STG(pAs, 1, 0, 16384);
  STG(pBs, 0, 0, 32768);
  STG(pBs, 1, 0, 49152);
  STG(pBs, 0, 1, 65536 + 32768);
  STG(pBs, 1, 1, 65536 + 49152);
  asm volatile("s_waitcnt vmcnt(4)" ::: "memory");
  BAR();

  for (int it = 0; it < 8; ++it) {
    const int t1 = 2 * it + 1, t2 = 2 * it + 2, t3 = 2 * it + 3;
    const bool st = (it < 7);
    LDA_Q(0, 0); LDB_Q(0, 0);
    STG(pAs, 0, t1, 65536);
    BAR(); LGKM0(); MFMA_Q(0, 0); BAR();
    LDB_Q(0, 1);
    STG(pAs, 1, t1, 65536 + 16384);
    BAR(); LGKM0(); MFMA_Q(0, 1); BAR();
    LDA_Q(0, 1);
    if (st) STG(pBs, 0, t2, 32768);
    BAR(); LGKM0(); MFMA_Q(1, 0); BAR();
    if (st) STG(pBs, 1, t2, 49152);
    BAR(); LGKM0(); MFMA_Q(1, 1);
    if (st) { asm volatile("s_waitcnt vmcnt(4)" ::: "memory"); }
    else    { asm volatile("s_waitcnt vmcnt(0)" ::: "memory"); }
    BAR();
    LDA_Q(65536, 0); LDB_Q(65536, 0);
    if (st) STG(pAs, 0, t2, 0);
    BAR(); LGKM0(); MFMA_Q(0, 0); BAR();
    LDB_Q(65536, 1);
    if (st) STG(pAs, 1, t2, 16384);
    BAR(); LGKM0(); MFMA_Q(0, 1); BAR();
    LDA_Q(65536, 1);
    if (st) STG(pBs, 0, t3, 65536 + 32768);
    BAR(); LGKM0(); MFMA_Q(1, 0); BAR();
    if (st) STG(pBs, 1, t3, 65536 + 49152);
    BAR(); LGKM0(); MFMA_Q(1, 1);
    if (st) { asm volatile("s_waitcnt vmcnt(4)" ::: "memory"); }
    else    { asm volatile("s_waitcnt vmcnt(0)" ::: "memory"); }
    BAR();
  }
#undef STG
#undef LDA_Q
#undef LDB_Q
#undef MFMA_Q
#undef BAR
#undef LGKM0

  // ---- epilogue: LDS transpose -> contiguous 1KB/wave NT stores ----
  // acc[M_][N_][j] maps to tile row = wr*128 + (M_>>2)*64 + (M_&3)*16 +
  // (lane>>4)*4 + j, col = wc*64 + (N_>>1)*32 + (N_&1)*16 + lr.
  // LDS layout per 128-row half: float[row][256], 16B slot s at col s*4
  // stored at slot s^(row&7) (2-way write conflict only).
  float* cl = (float*)lds;
#pragma unroll 1
  for (int hh = 0; hh < 2; ++hh) {
    __syncthreads();  // previous half's reads (or K-loop) complete
    if (wr == hh) {
#pragma unroll
      for (int M_ = 0; M_ < 8; M_++) {
        const int rr = (M_ >> 2) * 64 + (M_ & 3) * 16 + ((lane >> 4) << 2);
#pragma unroll
        for (int N_ = 0; N_ < 4; N_++) {
          const int cc = wc * 64 + (N_ >> 1) * 32 + (N_ & 1) * 16 + lr;
#pragma unroll
          for (int j = 0; j < 4; j++) {
            const int r = rr + j;
            cl[r * 256 + (cc ^ ((r & 7) << 2))] = acc[M_][N_][j];
          }
        }
      }
    }
    __syncthreads();  // half visible to all waves
#pragma unroll 1
    for (int it2 = 0; it2 < 16; ++it2) {
      const int lin = it2 * 512 + tid;   // one wave = one full row (1KB)
      const int row = lin >> 6;
      const int s = lin & 63;
      const f32x4 v = *(const f32x4*)(cl + row * 256 + ((s ^ (row & 7)) << 2));
      const int g = tn + (s << 2);
      const size_t go = (size_t)(tm + hh * 128 + row) * Nreal + g;
      if (g + 3 < Nreal) {
        __builtin_nontemporal_store(v, (f32x4*)(C + go));
      } else if (g < Nreal) {
#pragma unroll
        for (int e = 0; e < 4; e++)
          if (g + e < Nreal) C[go + e] = v[e];
      }
    }
  }
}

// ---------------------------------------------------------------------------
// Host
// ---------------------------------------------------------------------------
extern "C" void kernel_launch(void* const* d_in, const int* in_sizes, int n_in,
                              void* d_out, int out_size, void* d_ws, size_t ws_size,
                              hipStream_t stream) {
  const int D = 1024, V = 50257, L = 8;
  const int M = 4096;
  const int Vpad = 50432;  // 197 * 256
  const size_t MD = (size_t)M * D;

  const int* ids = (const int*)d_in[0];
  const float* embedw = (const float*)d_in[1];
  const float* norm1_w = (const float*)d_in[2];
  const float* norm2_w = (const float*)d_in[3];
  const float* a_diag = (const float*)d_in[4];
  const float* W_in = (const float*)d_in[5];
  const float* b_in = (const float*)d_in[6];
  const float* W_out = (const float*)d_in[7];
  const float* ff_w1 = (const float*)d_in[8];
  const float* ff_b1 = (const float*)d_in[9];
  const float* ff_w2 = (const float*)d_in[10];
  const float* ff_b2 = (const float*)d_in[11];
  const float* final_norm_w = (const float*)d_in[12];
  const float* lm_head_w = (const float*)d_in[13];

  char* w = (char*)d_ws;
  float* x = (float*)w;   w += MD * 4;
  u16* h = (u16*)w;       w += MD * 2;
  float* pre = (float*)w; w += MD * 4;
  u16* hs = (u16*)w;      w += MD * 2;
  u16* hff = (u16*)w;     w += MD * 2 * 2;
  u16* WinT = (u16*)w;    w += (size_t)L * D * D * 2;
  u16* WoutT = (u16*)w;   w += (size_t)L * D * D * 2;
  u16* ffw1T = (u16*)w;   w += (size_t)L * 2 * D * D * 2;
  u16* ffw2T = (u16*)w;   w += (size_t)L * 2 * D * D * 2;
  u16* lmpad = (u16*)w;   w += (size_t)Vpad * D * 2;

  // weight prep
  lm_cast_kernel<<<Vpad, 256, 0, stream>>>(lm_head_w, lmpad);
  transpose_cast_kernel<<<dim3(32, 32, L), dim3(32, 8), 0, stream>>>(W_in, WinT, D, D);
  transpose_cast_kernel<<<dim3(64, 32, L), dim3(32, 8), 0, stream>>>(ff_w1, ffw1T, D, 2 * D);
  transpose_cast_kernel<<<dim3(32, 32, L), dim3(32, 8), 0, stream>>>(W_out, WoutT, D, D);
  transpose_cast_kernel<<<dim3(32, 64, L), dim3(32, 8), 0, stream>>>(ff_w2, ffw2T, 2 * D, D);

  embed_kernel<<<M, 256, 0, stream>>>(ids, embedw, x);

  for (int l = 0; l < L; l++) {
    rmsnorm_kernel<<<M, 256, 0, stream>>>(x, norm1_w + (size_t)l * D, h);
    gemmL<0><<<dim3(8, 64), 256, 0, stream>>>(
        h, D, WinT + (size_t)l * D * D, D, nullptr, pre, nullptr, D, D);
    scan_kernel<<<8, 256, 0, stream>>>(pre, a_diag + (size_t)l * D,
                                       b_in + (size_t)l * D, hs);
    gemmL<1><<<dim3(8, 64), 256, 0, stream>>>(
        hs, D, WoutT + (size_t)l * D * D, D, nullptr, x, nullptr, D, D);
    rmsnorm_kernel<<<M, 256, 0, stream>>>(x, norm2_w + (size_t)l * D, h);
    gemmL<2><<<dim3(16, 64), 256, 0, stream>>>(
        h, D, ffw1T + (size_t)l * 2 * D * D, D, ff_b1 + (size_t)l * 2 * D,
        nullptr, hff, 2 * D, D);
    gemmL<3><<<dim3(8, 64), 256, 0, stream>>>(
        hff, 2 * D, ffw2T + (size_t)l * 2 * D * D, 2 * D,
        ff_b2 + (size_t)l * D, x, nullptr, D, 2 * D);
  }

  rmsnorm_kernel<<<M, 256, 0, stream>>>(x, final_norm_w, h);
  gemm_lm8<<<dim3(8 * 394), 512, 0, stream>>>(h, lmpad, (float*)d_out, V);
}